// Round 3
// 516.561 us; speedup vs baseline: 1.0695x; 1.0695x over previous
//
#include <hip/hip_runtime.h>

// EM routing (matrix capsules), B=16,H=6,W=6,KH=KW=3,I=32,O=32,A=4, ITERATIONS=2.
//
// R5 = R4 + butterfly wave-max fix. (Resubmitted verbatim after infra failure
// in round 2 — container acquisition failed; kernel itself was never run.)
//  K1: (site, p-quarter) float4 streaming moments -> mu1/i2s/base/m1 tables. (unchanged)
//  K3: (site, 4-i group), 256 thr. Thread (kk=t>>5, o=t&31) loads its vote row
//      slice votes[site,kk,i,o,0:16] DIRECTLY from global (4x dwordx4, contiguous
//      64B/lane => full line use; no LDS staging, no s_V). mu/i2s tables loaded
//      per-thread from global (L2/L3-hot from K1, site order reversed). LSE uses
//      per-wave (max, sumexp) partials + parity-double-buffered 8-float LDS slot
//      => ONE barrier per i (was 3). Wave max via BUTTERFLY shfl_xor so every
//      lane holds the true max (R4 bug: shfl_down tree is lane-0-only valid).
//      kk=8 tail row reloaded after logden (L1 hit) instead of 16 live VGPRs.
//      Block-end shfl+LDS reduction -> 33x32 partial per block.
//  K4: sum 8 partials/site, 0.2*M1 mix, finalize mu2/sig2/a_j2. (unchanged)
// Fixed harness overhead (ws poison 205us + in restore ~100us) is untouchable;
// kernels target the 2x votes-pass HBM floor (~115us).

#define KKc 9
#define NIc 32
#define NOc 32
#define NAc 16
#define KIc 288    // KKc*NIc
#define NPc 512    // NOc*NAc
#define NSITE 576

#define EPSf 1e-7f
#define TWO_PIf 6.28318530717958647692f

__device__ __forceinline__ float wave_sum(float v) {     // valid in lane 0 only
#pragma unroll
  for (int off = 32; off; off >>= 1) v += __shfl_down(v, off, 64);
  return v;
}
__device__ __forceinline__ float wave_max_all(float v) { // butterfly: valid in ALL lanes
#pragma unroll
  for (int off = 32; off; off >>= 1) v = fmaxf(v, __shfl_xor(v, off, 64));
  return v;
}

// ---------------- K1: M-step-1 ----------------
// grid 2304 = site*4+qtr; block 128. Thread owns float4 col c = qtr*32+(t&31),
// rows ki = (t>>5) + 4k. Cross-row fold: shfl_xor(32) then 1 LDS hop.
__global__ __launch_bounds__(128)
void em_k1(const float* __restrict__ votes, const float* __restrict__ acts_in,
           const float* __restrict__ beta_a, const float* __restrict__ beta_u,
           float* __restrict__ w_mu1, float* __restrict__ w_i2s,
           float* __restrict__ w_m1v, float* __restrict__ w_m1q,
           float* __restrict__ w_base, float* __restrict__ w_sR1)
{
  const int site = blockIdx.x >> 2;
  const int qtr  = blockIdx.x & 3;
  const int t    = threadIdx.x;

  __shared__ float s_act[KIc];
  __shared__ float s_red[2];
  __shared__ float s_cr[32 * 9];

  s_act[t] = acts_in[site * KIc + t];
  s_act[t + 128] = acts_in[site * KIc + t + 128];
  if (t < 32) s_act[t + 256] = acts_in[site * KIc + t + 256];
  __syncthreads();

  float v = fmaf(0.8f, s_act[t], 0.2f) + fmaf(0.8f, s_act[t + 128], 0.2f);
  if (t < 32) v += fmaf(0.8f, s_act[t + 256], 0.2f);
  v = wave_sum(v);
  if ((t & 63) == 0) s_red[t >> 6] = v;
  __syncthreads();
  const float sumR1 = (s_red[0] + s_red[1]) * 0.03125f;

  const int c  = qtr * 32 + (t & 31);   // float4 column 0..127
  const int r0 = t >> 5;                // 0..3
  float pv0 = 0.f, pv1 = 0.f, pv2 = 0.f, pv3 = 0.f;
  float pq0 = 0.f, pq1 = 0.f, pq2 = 0.f, pq3 = 0.f;
  const float4* vb = reinterpret_cast<const float4*>(votes) + (size_t)site * (KIc * 128) + c;
#pragma unroll 8
  for (int k = 0; k < 72; ++k) {
    const int ki = r0 + 4 * k;
    const float r = fmaf(0.8f, s_act[ki], 0.2f) * 0.03125f;
    const float4 x = vb[(size_t)ki * 128];
    pv0 = fmaf(r, x.x, pv0); pq0 = fmaf(r, x.x * x.x, pq0);
    pv1 = fmaf(r, x.y, pv1); pq1 = fmaf(r, x.y * x.y, pq1);
    pv2 = fmaf(r, x.z, pv2); pq2 = fmaf(r, x.z * x.z, pq2);
    pv3 = fmaf(r, x.w, pv3); pq3 = fmaf(r, x.w * x.w, pq3);
  }
  // fold rows r0 pairs within wave
  pv0 += __shfl_xor(pv0, 32); pv1 += __shfl_xor(pv1, 32);
  pv2 += __shfl_xor(pv2, 32); pv3 += __shfl_xor(pv3, 32);
  pq0 += __shfl_xor(pq0, 32); pq1 += __shfl_xor(pq1, 32);
  pq2 += __shfl_xor(pq2, 32); pq3 += __shfl_xor(pq3, 32);
  if (t >= 64 && t < 96) {
    const int l = t - 64;
    s_cr[l * 9 + 0] = pv0; s_cr[l * 9 + 1] = pv1; s_cr[l * 9 + 2] = pv2; s_cr[l * 9 + 3] = pv3;
    s_cr[l * 9 + 4] = pq0; s_cr[l * 9 + 5] = pq1; s_cr[l * 9 + 6] = pq2; s_cr[l * 9 + 7] = pq3;
  }
  __syncthreads();
  if (t < 32) {
    pv0 += s_cr[t * 9 + 0]; pv1 += s_cr[t * 9 + 1]; pv2 += s_cr[t * 9 + 2]; pv3 += s_cr[t * 9 + 3];
    pq0 += s_cr[t * 9 + 4]; pq1 += s_cr[t * 9 + 5]; pq2 += s_cr[t * 9 + 6]; pq3 += s_cr[t * 9 + 7];

    const float sR1e = sumR1 + EPSf;
    const float sR1x = sumR1 + 2.f * EPSf;
    const float mu0 = pv0 / sR1e, mu1 = pv1 / sR1e, mu2 = pv2 / sR1e, mu3 = pv3 / sR1e;
    const float sg0 = fmaxf((pq0 - mu0 * mu0 * sR1x) / sR1e, 0.f);
    const float sg1 = fmaxf((pq1 - mu1 * mu1 * sR1x) / sR1e, 0.f);
    const float sg2 = fmaxf((pq2 - mu2 * mu2 * sR1x) / sR1e, 0.f);
    const float sg3 = fmaxf((pq3 - mu3 * mu3 * sR1x) / sR1e, 0.f);

    const size_t fo = (size_t)site * 128 + c;
    reinterpret_cast<float4*>(w_mu1)[fo] = make_float4(mu0, mu1, mu2, mu3);
    reinterpret_cast<float4*>(w_i2s)[fo] = make_float4(0.5f / sg0, 0.5f / sg1, 0.5f / sg2, 0.5f / sg3);
    reinterpret_cast<float4*>(w_m1v)[fo] = make_float4(pv0, pv1, pv2, pv3);
    reinterpret_cast<float4*>(w_m1q)[fo] = make_float4(pq0, pq1, pq2, pq3);

    const int o = c >> 2;
    const float bu = beta_u[o];
    float lt = logf(TWO_PIf * sg0 + EPSf) + logf(TWO_PIf * sg1 + EPSf)
             + logf(TWO_PIf * sg2 + EPSf) + logf(TWO_PIf * sg3 + EPSf);
    float ch = (4.f * bu - 0.5f * (logf(sg0 + EPSf) + logf(sg1 + EPSf)
                                 + logf(sg2 + EPSf) + logf(sg3 + EPSf))) * sumR1;
    ch += __shfl_xor(ch, 1); ch += __shfl_xor(ch, 2);
    lt += __shfl_xor(lt, 1); lt += __shfl_xor(lt, 2);
    if ((t & 3) == 0) {
      // inv_temp (it=0) = 0.01*(1-0.95) = 0.0005
      const float aj = 1.f / (1.f + expf(-(0.0005f * (beta_a[o] - ch))));
      w_base[site * NOc + o] = logf(aj + EPSf) - lt;
    }
    if (t == 0) w_sR1[site] = sumR1;
  }
}

// ---------------- K3: E-step + M-step-2 partials (register-direct) ----------------
// grid 4608; block 256. site reversed for L2/L3 reuse of K1's tail.
// Thread (kk = t>>5, o = t&31) owns votes[site,kk,i,o,0:16] (contiguous 64B).
// t<32 additionally owns the kk=8 tail row.
__global__ __launch_bounds__(256)
void em_k3(const float* __restrict__ votes, const float* __restrict__ acts_in,
           const float* __restrict__ w_mu1, const float* __restrict__ w_i2s,
           const float* __restrict__ w_base, float* __restrict__ w_part)
{
  const int site = (NSITE - 1) - (blockIdx.x >> 3);
  const int ig   = blockIdx.x & 7;
  const int t    = threadIdx.x;
  const int o    = t & 31;
  const int kk   = t >> 5;          // 0..7

  __shared__ float s_act[KIc];
  __shared__ float s_lse[2][8];     // [parity][wave*2 + {max, sumexp}]
  __shared__ float s_p[33 * 128];   // 16896B block-reduction buffer

  s_act[t] = acts_in[site * KIc + t];
  if (t < 32) s_act[256 + t] = acts_in[site * KIc + 256 + t];
  // (visibility of s_act is covered by the first in-loop barrier)

  // per-thread mu/i2s tables for capsule o, straight from global (L2/L3-hot)
  float mu[16], is[16];
  {
    const float4* mp = reinterpret_cast<const float4*>(w_mu1 + (size_t)site * NPc) + o * 4;
    const float4* ip = reinterpret_cast<const float4*>(w_i2s + (size_t)site * NPc) + o * 4;
#pragma unroll
    for (int j = 0; j < 4; ++j) {
      const float4 a = mp[j];
      mu[4 * j] = a.x; mu[4 * j + 1] = a.y; mu[4 * j + 2] = a.z; mu[4 * j + 3] = a.w;
      const float4 b = ip[j];
      is[4 * j] = b.x; is[4 * j + 1] = b.y; is[4 * j + 2] = b.z; is[4 * j + 3] = b.w;
    }
  }
  const float lbase = w_base[site * NOc + o];

  float accv[16], accq[16], accw = 0.f;
#pragma unroll
  for (int a = 0; a < 16; ++a) { accv[a] = 0.f; accq[a] = 0.f; }

  const float4* vrow = reinterpret_cast<const float4*>(votes)
                     + (size_t)site * (KIc * 128) + o * 4;

  for (int ii = 0; ii < 4; ++ii) {
    const int i = ig * 4 + ii;

    // own row -> registers (4x dwordx4, 64B contiguous per lane)
    float v1[16];
    {
      const float4* p1 = vrow + (size_t)(kk * NIc + i) * 128;
#pragma unroll
      for (int j = 0; j < 4; ++j) {
        const float4 x = p1[j];
        v1[4 * j] = x.x; v1[4 * j + 1] = x.y; v1[4 * j + 2] = x.z; v1[4 * j + 3] = x.w;
      }
    }
    float lp1 = 0.f;
#pragma unroll
    for (int a = 0; a < 16; ++a) { const float d = v1[a] - mu[a]; lp1 = fmaf(d * d, is[a], lp1); }
    const float ln1 = lbase - lp1;

    // kk=8 tail (lanes 0-31 of wave 0): compute ln2 without keeping v2 live
    float ln2 = -1e30f;
    if (t < 32) {
      const float4* p2 = vrow + (size_t)(8 * NIc + i) * 128;
      float lp2 = 0.f;
#pragma unroll
      for (int j = 0; j < 4; ++j) {
        const float4 x = p2[j];
        float d;
        d = x.x - mu[4 * j];     lp2 = fmaf(d * d, is[4 * j],     lp2);
        d = x.y - mu[4 * j + 1]; lp2 = fmaf(d * d, is[4 * j + 1], lp2);
        d = x.z - mu[4 * j + 2]; lp2 = fmaf(d * d, is[4 * j + 2], lp2);
        d = x.w - mu[4 * j + 3]; lp2 = fmaf(d * d, is[4 * j + 3], lp2);
      }
      ln2 = lbase - lp2;
    }

    // per-wave LSE partials -> single barrier -> register combine.
    // mw must be valid in ALL lanes (every lane uses it for its exp term).
    const float mw = wave_max_all(fmaxf(ln1, ln2));
    float e = expf(ln1 - mw) + ((t < 32) ? expf(ln2 - mw) : 0.f);
    e = wave_sum(e);                       // lane 0 holds the wave total
    if ((t & 63) == 0) {
      s_lse[ii & 1][(t >> 6) * 2 + 0] = mw;
      s_lse[ii & 1][(t >> 6) * 2 + 1] = e;
    }
    __syncthreads();
    const float m0 = s_lse[ii & 1][0], e0 = s_lse[ii & 1][1];
    const float m1 = s_lse[ii & 1][2], e1 = s_lse[ii & 1][3];
    const float m2 = s_lse[ii & 1][4], e2 = s_lse[ii & 1][5];
    const float m3 = s_lse[ii & 1][6], e3 = s_lse[ii & 1][7];
    const float gm = fmaxf(fmaxf(m0, m1), fmaxf(m2, m3));
    const float den = e0 * expf(m0 - gm) + e1 * expf(m1 - gm)
                    + e2 * expf(m2 - gm) + e3 * expf(m3 - gm);
    const float logden = gm + logf(den);

    // weights + moment accumulation, all registers
    const float w1 = expf(ln1 - logden) * s_act[kk * NIc + i] * 0.8f;
    accw += w1;
#pragma unroll
    for (int a = 0; a < 16; ++a) {
      accv[a] = fmaf(w1, v1[a], accv[a]);
      accq[a] = fmaf(w1, v1[a] * v1[a], accq[a]);
    }
    if (t < 32) {
      const float w2 = expf(ln2 - logden) * s_act[8 * NIc + i] * 0.8f;
      accw += w2;
      const float4* p2 = vrow + (size_t)(8 * NIc + i) * 128;
#pragma unroll
      for (int j = 0; j < 4; ++j) {
        const float4 x = p2[j];   // L1/L2-hot reload, saves 16 live VGPRs
        accv[4 * j]     = fmaf(w2, x.x, accv[4 * j]);
        accq[4 * j]     = fmaf(w2, x.x * x.x, accq[4 * j]);
        accv[4 * j + 1] = fmaf(w2, x.y, accv[4 * j + 1]);
        accq[4 * j + 1] = fmaf(w2, x.y * x.y, accq[4 * j + 1]);
        accv[4 * j + 2] = fmaf(w2, x.z, accv[4 * j + 2]);
        accq[4 * j + 2] = fmaf(w2, x.z * x.z, accq[4 * j + 2]);
        accv[4 * j + 3] = fmaf(w2, x.w, accv[4 * j + 3]);
        accq[4 * j + 3] = fmaf(w2, x.w * x.w, accq[4 * j + 3]);
      }
    }
  }

  // ---- block reduction over kk: shfl fold + 4-wave LDS combine ----
  accw += __shfl_xor(accw, 32);
#pragma unroll
  for (int a = 0; a < 16; ++a) {
    accv[a] += __shfl_xor(accv[a], 32);
    accq[a] += __shfl_xor(accq[a], 32);
  }
  {
    const int l = t & 63, wv = t >> 6;
    if (l < 32) {
#pragma unroll
      for (int a = 0; a < 16; ++a) {
        s_p[a * 128 + wv * 32 + l] = accv[a];
        s_p[(16 + a) * 128 + wv * 32 + l] = accq[a];
      }
      s_p[32 * 128 + wv * 32 + l] = accw;
    }
  }
  __syncthreads();
  float* wp = w_part + (size_t)(site * 8 + ig) * (33 * 32);
  for (int j = t >> 5; j < 33; j += 8) {
    const float s = s_p[j * 128 + o] + s_p[j * 128 + 32 + o]
                  + s_p[j * 128 + 64 + o] + s_p[j * 128 + 96 + o];
    wp[j * 32 + o] = s;
  }
}

// ---------------- K4: finalize ----------------
__global__ __launch_bounds__(256)
void em_k4(const float* __restrict__ beta_a, const float* __restrict__ beta_u,
           const float* __restrict__ w_m1v, const float* __restrict__ w_m1q,
           const float* __restrict__ w_sR1, const float* __restrict__ w_part,
           float* __restrict__ out)
{
  const int site = blockIdx.x;
  const int t    = threadIdx.x;
  const int oB   = t & 31;
  const int a2B  = (t >> 5) * 2;

  __shared__ float s_M[33 * 32];
  __shared__ float s_c[256];

  for (int j = t >> 5; j < 33; j += 8) {
    float s = 0.f;
#pragma unroll
    for (int g = 0; g < 8; ++g)
      s += w_part[(size_t)(site * 8 + g) * (33 * 32) + j * 32 + oB];
    s_M[j * 32 + oB] = s;
  }
  __syncthreads();

  const float sumR1 = w_sR1[site];
  const float sumR  = s_M[32 * 32 + oB] + 0.2f * sumR1;
  const float sRe   = sumR + EPSf;
  const float sRx   = sumR + 2.f * EPSf;
  const int p = oB * NAc + a2B;

  const float Mva = s_M[a2B * 32 + oB]        + 0.2f * w_m1v[(size_t)site * NPc + p];
  const float Mvb = s_M[(a2B + 1) * 32 + oB]  + 0.2f * w_m1v[(size_t)site * NPc + p + 1];
  const float Mqa = s_M[(16 + a2B) * 32 + oB] + 0.2f * w_m1q[(size_t)site * NPc + p];
  const float Mqb = s_M[(17 + a2B) * 32 + oB] + 0.2f * w_m1q[(size_t)site * NPc + p + 1];

  const float mua = Mva / sRe;
  const float mub = Mvb / sRe;
  const float sga = fmaxf((Mqa - mua * mua * sRx) / sRe, 0.f);
  const float sgb = fmaxf((Mqb - mub * mub * sRx) / sRe, 0.f);

  reinterpret_cast<float2*>(out + (size_t)site * NPc)[p >> 1] = make_float2(mua, mub);

  const float bu = beta_u[oB];
  s_c[t] = (bu - 0.5f * logf(sga + EPSf)) * sumR
         + (bu - 0.5f * logf(sgb + EPSf)) * sumR;
  __syncthreads();
  if (t < NOc) {
    float c = 0.f;
#pragma unroll
    for (int k = 0; k < 8; ++k) c += s_c[t + 32 * k];
    // inv_temp (it_idx=ITERATIONS=2) = 0.01*(1-0.95^3) = 0.00142625
    const float aj = 1.f / (1.f + expf(-(0.00142625f * (beta_a[t] - c))));
    out[(size_t)NSITE * NPc + site * NOc + t] = aj;
  }
}

extern "C" void kernel_launch(void* const* d_in, const int* in_sizes, int n_in,
                              void* d_out, int out_size, void* d_ws, size_t ws_size,
                              hipStream_t stream) {
  const float* votes  = (const float*)d_in[0];
  const float* acts   = (const float*)d_in[1];
  const float* beta_a = (const float*)d_in[2];
  const float* beta_u = (const float*)d_in[3];
  float* out = (float*)d_out;

  float* ws = (float*)d_ws;
  const size_t SP = (size_t)NSITE * NPc;        // 294912
  float* w_mu1  = ws;
  float* w_i2s  = ws + SP;
  float* w_m1v  = ws + 2 * SP;
  float* w_m1q  = ws + 3 * SP;
  float* w_base = ws + 4 * SP;                  // 576*32
  float* w_sR1  = w_base + NSITE * NOc;         // 576 (padded to 1024)
  float* w_part = w_sR1 + 1024;                 // 4608*33*32 floats (~19.5MB)

  em_k1<<<NSITE * 4, 128, 0, stream>>>(votes, acts, beta_a, beta_u,
                                       w_mu1, w_i2s, w_m1v, w_m1q, w_base, w_sR1);
  em_k3<<<NSITE * 8, 256, 0, stream>>>(votes, acts, w_mu1, w_i2s, w_base, w_part);
  em_k4<<<NSITE, 256, 0, stream>>>(beta_a, beta_u, w_m1v, w_m1q, w_sR1, w_part, out);
}